// Round 2
// baseline (470.458 us; speedup 1.0000x reference)
//
#include <hip/hip_runtime.h>

#define NEG_INF (-1e9f)
#define SCALE_F 0.08838834764831845f

typedef __attribute__((ext_vector_type(8))) short short8;
typedef __attribute__((ext_vector_type(4))) float float4v;

__device__ __constant__ int cDR[8] = {1,1,0,-1,-1,-1,0,1};
__device__ __constant__ int cDC[8] = {0,1,1,1,0,-1,-1,-1};
__device__ __constant__ int cKR[8] = {2,1,-1,-2,-2,-1,1,2};
__device__ __constant__ int cKC[8] = {1,2,2,1,-1,-2,-2,-1};

__device__ __forceinline__ ushort f2bf(float f) {
  union { float f; unsigned u; } a; a.f = f;
  unsigned u = a.u;
  return (ushort)((u + 0x7FFFu + ((u >> 16) & 1u)) >> 16);
}

// truncation-pack 8 f32 -> 8 bf16 (error 2^-8, irrelevant vs threshold)
__device__ __forceinline__ short8 pack8(float4 a, float4 b) {
  union { short8 v; unsigned u[4]; } o;
  unsigned a0 = __float_as_uint(a.x), a1 = __float_as_uint(a.y);
  unsigned a2 = __float_as_uint(a.z), a3 = __float_as_uint(a.w);
  unsigned b0 = __float_as_uint(b.x), b1 = __float_as_uint(b.y);
  unsigned b2 = __float_as_uint(b.z), b3 = __float_as_uint(b.w);
  o.u[0] = (a1 & 0xFFFF0000u) | (a0 >> 16);
  o.u[1] = (a3 & 0xFFFF0000u) | (a2 >> 16);
  o.u[2] = (b1 & 0xFFFF0000u) | (b0 >> 16);
  o.u[3] = (b3 & 0xFFFF0000u) | (b2 >> 16);
  return o.v;
}

// Wsw layout (LINEAR, no swizzle — consumed directly from L2, never via LDS):
// [kc][row][kin] bf16, chunk-major (18432 elems = 36864 B per chunk).
// row 0..287: 0-127 Wq cols, 128-255 Wk cols, 256-264 Wu cols, 265-287 zero.
__global__ void wconv_kernel(const float* __restrict__ Wq,
                             const float* __restrict__ Wk,
                             const float* __restrict__ Wu,
                             ushort* __restrict__ Wsw) {
  int row = blockIdx.x;  // 0..287
  for (int k = threadIdx.x; k < 1024; k += 256) {
    float v;
    if (row < 128)      v = Wq[k * 128 + row];
    else if (row < 256) v = Wk[k * 128 + (row - 128)];
    else if (row < 265) v = Wu[k * 9 + (row - 256)];
    else                v = 0.f;
    int kc = k >> 6, kin = k & 63;
    Wsw[(size_t)kc * 18432 + row * 64 + kin] = f2bf(v);
  }
}

// 1 elem/block. x is reg-staged (global->VGPR->bf16->LDS, T14 issue-early /
// write-late: chunk k+1 loads issue before compute(k), pack+ds_write after).
// W B-fragments load straight from L2 to registers (no intra-block reuse ->
// LDS staging of W was pure overhead). One __syncthreads per chunk; nothing
// outstanding at the barrier (loads consumed by pack before it).
__global__ __launch_bounds__(256, 3)
void apol_main(const float* __restrict__ x,
               const float* __restrict__ bq,
               const float* __restrict__ bk,
               const float* __restrict__ bu,
               const ushort* __restrict__ Wsw,
               float* __restrict__ out) {
  // LDS union:
  //  phase1: xs bf16[2][64][64] double-buffer (2 x 8192 B)         = 16384 B
  //  phase2: qs[64][132] + ks[64][132] bf16                        = 33792 B
  //  phase3: Sl f32[64][65]                                        = 16640 B
  __shared__ __align__(16) char smem[33792];
  char*   xs0 = smem;
  char*   xs1 = smem + 8192;
  ushort* qs  = (ushort*)smem;
  ushort* ks  = (ushort*)(smem + 16896);
  float*  Sl  = (float*)smem;

  const int tid = threadIdx.x;
  const int w = tid >> 6, lane = tid & 63;
  const int l15 = lane & 15, qd = lane >> 4;
  const char* xb = (const char*)(x + (size_t)blockIdx.x * 65536);
  const char* WsB = (const char*)Wsw;

  // x stage: wave w owns rows w*16..w*16+15; lane handles row w*16+(lane>>2),
  // 16 consecutive f32 at col (lane&3)*16 -> 2 bf16 granules of 16B.
  const int srow = w * 16 + (lane >> 2);
  const int scol4 = lane & 3;
  const char* xsrc = xb + srow * 4096 + scol4 * 64;  // + kc*256 per chunk
  // bf16 tile row stride 128B, 8 granules/row, XOR-swizzled by row&7.
  const int wr0 = srow * 128 + (((scol4 * 2 + 0) ^ (srow & 7)) * 16);
  const int wr1 = srow * 128 + (((scol4 * 2 + 1) ^ (srow & 7)) * 16);

  // A-frag read: row=mt*16+l15, granule kk*4+qd, same swizzle key (row&7=l15&7)
  const int arow = l15 * 128;
  int aoff[2];
  #pragma unroll
  for (int kk = 0; kk < 2; ++kk)
    aoff[kk] = (((kk * 4 + qd) ^ (l15 & 7)) * 16);

  // W global voffsets: row=(w*64+nt*16+l15), byte = row*128 + (kk*4+qd)*16.
  // nt*2048 + kk*64 folds into the load's immediate offset.
  const int wvo = (w * 64 + l15) * 128 + qd * 16;
  const int uvo = (256 + l15) * 128 + qd * 16;

  float4v acc[4][4];
  #pragma unroll
  for (int i = 0; i < 4; ++i)
    #pragma unroll
    for (int j = 0; j < 4; ++j)
      acc[i][j] = (float4v){0.f, 0.f, 0.f, 0.f};
  float4v aup = (float4v){0.f, 0.f, 0.f, 0.f};

  // prologue: stage chunk 0
  {
    float4 g0 = *(const float4*)(xsrc);
    float4 g1 = *(const float4*)(xsrc + 16);
    float4 g2 = *(const float4*)(xsrc + 32);
    float4 g3 = *(const float4*)(xsrc + 48);
    *(short8*)(xs0 + wr0) = pack8(g0, g1);
    *(short8*)(xs0 + wr1) = pack8(g2, g3);
  }
  __syncthreads();

  // ---------------- GEMM1: 16 chunks of BK=64 ----------------
  #pragma unroll 1
  for (int kc = 0; kc < 16; ++kc) {
    const char* xcur = (kc & 1) ? xs1 : xs0;
    char* xnxt = (kc & 1) ? xs0 : xs1;
    // issue next-chunk x loads early; HBM latency hides under compute below
    float4 g0, g1, g2, g3;
    const bool pf = (kc < 15);
    if (pf) {
      const char* s = xsrc + (kc + 1) * 256;
      g0 = *(const float4*)(s);
      g1 = *(const float4*)(s + 16);
      g2 = *(const float4*)(s + 32);
      g3 = *(const float4*)(s + 48);
    }
    const char* wp = WsB + (size_t)kc * 36864;
    #pragma unroll
    for (int kk = 0; kk < 2; ++kk) {
      short8 bf[4];
      #pragma unroll
      for (int nt = 0; nt < 4; ++nt)
        bf[nt] = *(const short8*)(wp + wvo + nt * 2048 + kk * 64);
      short8 ub;
      if (w == 3) ub = *(const short8*)(wp + uvo + kk * 64);
      #pragma unroll
      for (int mt = 0; mt < 4; ++mt) {
        short8 af = *(const short8*)(xcur + mt * 2048 + arow + aoff[kk]);
        #pragma unroll
        for (int nt = 0; nt < 4; ++nt)
          acc[mt][nt] = __builtin_amdgcn_mfma_f32_16x16x32_bf16(
              af, bf[nt], acc[mt][nt], 0, 0, 0);
        if (w == 3 && mt == 3)
          aup = __builtin_amdgcn_mfma_f32_16x16x32_bf16(af, ub, aup, 0, 0, 0);
      }
    }
    // write-late: pack + store next chunk just before the barrier
    if (pf) {
      *(short8*)(xnxt + wr0) = pack8(g0, g1);
      *(short8*)(xnxt + wr1) = pack8(g2, g3);
    }
    __syncthreads();
  }

  float* outb = out + (size_t)blockIdx.x * 4672;

  // promo writes: wave 3, C rows 0..7 <-> x rows 48..55, cols 0..8
  if (w == 3 && qd < 2 && l15 < 9) {
    float bias = bu[l15];
    #pragma unroll
    for (int r = 0; r < 4; ++r) {
      int f = 48 + qd * 4 + r;
      outb[f * 73 + 64 + l15] = aup[r] + bias;
    }
  }

  // ---------------- epilogue: acc -> qs/ks (bias, scale) ----------------
  #pragma unroll
  for (int nt = 0; nt < 4; ++nt) {
    int C = w * 64 + nt * 16 + l15;
    bool isq = (C < 128);
    int p = isq ? C : (C - 128);
    float bias = isq ? bq[p] : bk[p];
    ushort* dstb = isq ? qs : ks;
    #pragma unroll
    for (int mt = 0; mt < 4; ++mt)
      #pragma unroll
      for (int r = 0; r < 4; ++r) {
        int row = mt * 16 + qd * 4 + r;
        float v = acc[mt][nt][r] + bias;
        if (isq) v *= SCALE_F;
        dstb[row * 132 + p] = f2bf(v);
      }
  }
  __syncthreads();

  // ---------------- GEMM2: S = q' @ k'^T (64x64), K=128 ----------------
  float4v acc2[4];
  #pragma unroll
  for (int nt = 0; nt < 4; ++nt) acc2[nt] = (float4v){0.f, 0.f, 0.f, 0.f};
  #pragma unroll
  for (int kp = 0; kp < 4; ++kp) {
    int kb = kp * 32 + qd * 8;
    short8 a2 = *(const short8*)((const char*)&qs[(w * 16 + l15) * 132 + kb]);
    #pragma unroll
    for (int nt = 0; nt < 4; ++nt) {
      short8 b2 = *(const short8*)((const char*)&ks[(nt * 16 + l15) * 132 + kb]);
      acc2[nt] = __builtin_amdgcn_mfma_f32_16x16x32_bf16(a2, b2, acc2[nt], 0, 0, 0);
    }
  }
  __syncthreads();
  #pragma unroll
  for (int nt = 0; nt < 4; ++nt)
    #pragma unroll
    for (int r = 0; r < 4; ++r)
      Sl[(w * 16 + qd * 4 + r) * 65 + nt * 16 + l15] = acc2[nt][r];
  __syncthreads();

  // ---------------- gather + masks + store ----------------
  for (int idx = tid; idx < 4672; idx += 256) {
    int f = idx / 73;
    int j = idx - f * 73;
    float val;
    if (j < 64) {
      int rr = f >> 3, cc = f & 7;
      int nr, nc;
      if (j < 56) {
        int d = j / 7;
        int dist = j - d * 7 + 1;
        nr = rr + cDR[d] * dist;
        nc = cc + cDC[d] * dist;
      } else {
        nr = rr + cKR[j - 56];
        nc = cc + cKC[j - 56];
      }
      val = (nr >= 0 && nr < 8 && nc >= 0 && nc < 8) ? Sl[f * 65 + nr * 8 + nc]
                                                     : NEG_INF;
    } else {
      if (f >= 48 && f < 56) continue;  // promo rows written from aup
      val = NEG_INF;
    }
    outb[idx] = val;
  }
}

extern "C" void kernel_launch(void* const* d_in, const int* in_sizes, int n_in,
                              void* d_out, int out_size, void* d_ws, size_t ws_size,
                              hipStream_t stream) {
  const float* x  = (const float*)d_in[0];
  const float* Wq = (const float*)d_in[1];
  const float* bq = (const float*)d_in[2];
  const float* Wk = (const float*)d_in[3];
  const float* bk = (const float*)d_in[4];
  const float* Wu = (const float*)d_in[5];
  const float* bu = (const float*)d_in[6];
  float* out = (float*)d_out;
  ushort* Wsw = (ushort*)d_ws;  // 16*18432 bf16 = 576 KB

  const int B = in_sizes[0] / 65536;

  wconv_kernel<<<288, 256, 0, stream>>>(Wq, Wk, Wu, Wsw);
  apol_main<<<B, 256, 0, stream>>>(x, bq, bk, bu, Wsw, out);
}